// Round 12
// baseline (27.658 us; speedup 1.0000x reference)
//
#include <hip/hip_runtime.h>
#include <hip/hip_bf16.h>

// SocialPooling, round 12 (resubmit — r2..r11 died on sandbox disk errors):
// branchless + unrolled inner loop, precomputed scene bounds (scene ids
// sorted, values in [0, 64)).
//
// out[i,g,h] = sum over j in scene(i), j!=i, |rel|<half-eps of ht[j,h],
// g = (rx>=0)*2 + (ry>=0)   (GRID_SIZE=2 makes floor((rel+half)/cell) trivial)

#define NUM_SCENES 64
#define HI_B  0.79f    // half - eps
#define LO_B -0.79f

// --- kernel 1: per-scene [start, end) from the sorted scene array ---
__global__ void scene_bounds_kernel(const int* __restrict__ scene,
                                    int* __restrict__ starts,
                                    int* __restrict__ ends, int n)
{
    int k = blockIdx.x * blockDim.x + threadIdx.x;
    if (k >= n) return;
    int s = scene[k];
    if (k == 0) {
        starts[s] = 0;
    } else {
        int sp = scene[k - 1];
        if (sp != s) { starts[s] = k; ends[sp] = k; }
    }
    if (k == n - 1) ends[s] = n;
}

// --- kernel 2: main pooling. 256 threads = 4 waves; wave w owns row
// i = blockIdx*4 + w; lane h owns hidden channel h. ---
__global__ __launch_bounds__(256) void social_pool_kernel(
    const float*  __restrict__ ht,      // (n, 64)
    const float2* __restrict__ pos,     // (n,) float2
    const int*    __restrict__ scene,   // (n,) sorted
    const int*    __restrict__ starts,  // (64,)
    const int*    __restrict__ ends,    // (64,)
    float*        __restrict__ out,     // (n, 4, 64)
    int n)
{
    const int wave = threadIdx.x >> 6;
    const int h    = threadIdx.x & 63;
    const int i    = blockIdx.x * 4 + wave;
    if (i >= n) return;

    const int s     = scene[i];
    const int start = starts[s];
    const int end   = ends[s];

    const float2 p  = pos[i];
    const float  px = p.x, py = p.y;

    float acc0 = 0.f, acc1 = 0.f, acc2 = 0.f, acc3 = 0.f;

    #pragma unroll 4
    for (int j = start; j < end; ++j) {
        const float2 q  = pos[j];                  // uniform addr -> scalar load
        const float  rx = q.x - px;
        const float  ry = q.y - py;
        const float  v  = ht[j * 64 + h];          // coalesced 256B, unconditional

        const bool in = (rx < HI_B) && (rx > LO_B) &&
                        (ry < HI_B) && (ry > LO_B) && (j != i);
        const float vv = in ? v : 0.f;             // one cndmask
        const bool xp = rx >= 0.f;
        const bool yp = ry >= 0.f;

        // route vv into exactly one accumulator (cndmask chains, no branches)
        acc0 += (!xp && !yp) ? vv : 0.f;
        acc1 += (!xp &&  yp) ? vv : 0.f;
        acc2 += ( xp && !yp) ? vv : 0.f;
        acc3 += ( xp &&  yp) ? vv : 0.f;
    }

    float* o = out + (long)i * 4 * 64 + h;
    o[0 * 64] = acc0;
    o[1 * 64] = acc1;
    o[2 * 64] = acc2;
    o[3 * 64] = acc3;
}

extern "C" void kernel_launch(void* const* d_in, const int* in_sizes, int n_in,
                              void* d_out, int out_size, void* d_ws, size_t ws_size,
                              hipStream_t stream)
{
    const float*  ht    = (const float*)d_in[0];   // (n,1,64) f32
    const float2* pos   = (const float2*)d_in[1];  // (n,1,2) f32
    const int*    scene = (const int*)d_in[2];     // (n,1) int sorted
    float*        out   = (float*)d_out;           // (n,4,64) f32

    const int n = in_sizes[2];                     // 4096

    int* starts = (int*)d_ws;
    int* ends   = starts + NUM_SCENES;

    scene_bounds_kernel<<<(n + 255) / 256, 256, 0, stream>>>(scene, starts, ends, n);
    social_pool_kernel<<<(n + 3) / 4, 256, 0, stream>>>(ht, pos, scene, starts, ends, out, n);
}